// Round 4
// baseline (526.011 us; speedup 1.0000x reference)
//
#include <hip/hip_runtime.h>

// Problem constants
#define NB   8
#define NC   256
#define HW   56
#define NPX  3136          // 56*56
#define RED  64
#define NG   16
#define GC   16
#define KS   7
#define KK   49
#define PADK 3
#define XPH  62            // padded rows: 3 + 56 + 3
#define XPW  64            // padded row stride: 3 + 56 + 5 (aligned)
#define XPSLICE (XPH * XPW)   // 3968 floats per channel slice

// ---------------------------------------------------------------------------
// K0: zero-padded copy of x into xpad[b][c][62][64].
// ---------------------------------------------------------------------------
__global__ __launch_bounds__(256) void pad_kernel(
    const float* __restrict__ x, float* __restrict__ xpad) {
    int bc = blockIdx.x;                       // 0 .. NB*NC-1
    const float* xs = x + (size_t)bc * NPX;
    float* xd = xpad + (size_t)bc * XPSLICE;
#pragma unroll 4
    for (int e = threadIdx.x; e < XPSLICE; e += 256) {
        int row = e >> 6, col = e & 63;
        int h = row - PADK, w = col - PADK;
        float v = (h >= 0 && h < HW && w >= 0 && w < HW) ? xs[h * HW + w] : 0.0f;
        xd[e] = v;
    }
}

// ---------------------------------------------------------------------------
// K1: t = relu(bn1(conv1x1(x, w1)))   x:[B][256][3136] -> t:[B][64][3136]
// Block = 256 threads (4 waves) = 4 rq-slices of the SAME 64-px tile.
// ---------------------------------------------------------------------------
__global__ __launch_bounds__(256) void conv1_kernel(
    const float* __restrict__ x, const float* __restrict__ w1,
    const float* __restrict__ g1, const float* __restrict__ be1,
    const float* __restrict__ mu1, const float* __restrict__ var1,
    float* __restrict__ t) {
    int lane = threadIdx.x & 63;
    int wv   = threadIdx.x >> 6;               // 0..3 (wave-uniform)
    int px = blockIdx.x * 64 + lane;
    int rq = blockIdx.y * 4 + wv;              // 0..7 -> outputs rq*8..rq*8+7
    int b  = blockIdx.z;

    const float* xb = x + (size_t)b * NC * NPX + px;
    float acc[8];
#pragma unroll
    for (int j = 0; j < 8; ++j) acc[j] = 0.0f;

#pragma unroll 1
    for (int c0 = 0; c0 < NC; c0 += 16) {
        float xv[16];
#pragma unroll
        for (int i = 0; i < 16; ++i) xv[i] = xb[(size_t)(c0 + i) * NPX];
#pragma unroll
        for (int j = 0; j < 8; ++j) {
            const float* wrow = w1 + (rq * 8 + j) * NC + c0;   // wave-uniform
#pragma unroll
            for (int i = 0; i < 16; ++i)
                acc[j] = fmaf(xv[i], wrow[i], acc[j]);
        }
    }

    float* tb = t + (size_t)b * RED * NPX + px;
#pragma unroll
    for (int j = 0; j < 8; ++j) {
        int o = rq * 8 + j;
        float inv = g1[o] * rsqrtf(var1[o] + 1e-5f);
        float v = acc[j] * inv + (be1[o] - mu1[o] * inv);
        tb[(size_t)o * NPX] = fmaxf(v, 0.0f);
    }
}

// ---------------------------------------------------------------------------
// K2: fused conv2(+bias) -> involution -> bn2 -> relu
// Grid (49 px-tiles, 4 group-quads, 8 batches), block 256 = 4 waves.
// All 4 waves share one 64-px tile; wave wv handles group gq*4+wv.
//  - t tile [64r][64px] staged in LDS (16 KB) once, conflict-free reads.
//  - Phase A: wgt[49] in regs (statically indexed; k-loop unrolled, r0 not).
//    tv[16] register batches from LDS; w2 rows are wave-uniform s_loads.
//  - Phase B: per channel ONE base pointer + 49 immediate-offset loads from
//    xpad (no masks, L1/L2 hits), 2 FMA chains, bn2+relu, coalesced store.
// ---------------------------------------------------------------------------
__global__ __launch_bounds__(256, 4) void involution_kernel(
    const float* __restrict__ xpad, const float* __restrict__ t,
    const float* __restrict__ w2, const float* __restrict__ b2,
    const float* __restrict__ g2, const float* __restrict__ be2,
    const float* __restrict__ mu2, const float* __restrict__ var2,
    float* __restrict__ out) {
    __shared__ float tls[RED * 64];            // [r][px] 16 KB

    int lane = threadIdx.x & 63;
    int wv   = threadIdx.x >> 6;               // 0..3 (wave-uniform)
    int px0  = blockIdx.x * 64;
    int gq   = blockIdx.y;                     // 0..3
    int b    = blockIdx.z;
    int px = px0 + lane;
    int h = px / HW, w = px % HW;

    // ---- stage t tile into LDS (coalesced 256B rows, conflict-free) ----
    const float* tb = t + (size_t)b * RED * NPX + px0;
#pragma unroll
    for (int rr = 0; rr < 16; ++rr) {
        int row = rr * 4 + wv;
        tls[row * 64 + lane] = tb[(size_t)row * NPX + lane];
    }
    __syncthreads();

    int g = gq * 4 + wv;                       // this wave's group
    const float* wg = w2 + (size_t)g * KK * RED;   // [49][64] wave-uniform
    const float* bg = b2 + g * KK;

    // ---- phase A: wgt[49] in registers ----
    float wgt[KK];
#pragma unroll
    for (int k = 0; k < KK; ++k) wgt[k] = bg[k];

#pragma unroll 1
    for (int r0 = 0; r0 < RED; r0 += 16) {
        float tv[16];
#pragma unroll
        for (int i = 0; i < 16; ++i) tv[i] = tls[(r0 + i) * 64 + lane];
#pragma unroll
        for (int k = 0; k < KK; ++k) {
            const float* wk = wg + k * RED + r0;   // wave-uniform s_load
#pragma unroll
            for (int i = 0; i < 16; ++i)
                wgt[k] = fmaf(tv[i], wk[i], wgt[k]);
        }
    }

    // ---- phase B: involution + bn2 + relu ----
    // tap (i,j) of pixel (h,w) reads padded (h+i, w+j) -> base (h,w), imm i*64+j
    const float* xgb = xpad + ((size_t)b * NC + (size_t)g * GC) * XPSLICE
                     + h * XPW + w;
    float* ob = out + ((size_t)b * NC + (size_t)g * GC) * NPX + px;

#pragma unroll 1
    for (int cl = 0; cl < GC; ++cl) {
        const float* xc = xgb + (size_t)cl * XPSLICE;
        float s0 = 0.0f, s1 = 0.0f;
#pragma unroll
        for (int i = 0; i < KS; ++i) {
            float x0 = xc[i * XPW + 0];
            float x1 = xc[i * XPW + 1];
            float x2 = xc[i * XPW + 2];
            float x3 = xc[i * XPW + 3];
            float x4 = xc[i * XPW + 4];
            float x5 = xc[i * XPW + 5];
            float x6 = xc[i * XPW + 6];
            s0 = fmaf(wgt[i * KS + 0], x0, s0);
            s1 = fmaf(wgt[i * KS + 1], x1, s1);
            s0 = fmaf(wgt[i * KS + 2], x2, s0);
            s1 = fmaf(wgt[i * KS + 3], x3, s1);
            s0 = fmaf(wgt[i * KS + 4], x4, s0);
            s1 = fmaf(wgt[i * KS + 5], x5, s1);
            s0 = fmaf(wgt[i * KS + 6], x6, s0);
        }
        float acc = s0 + s1;

        int c = g * GC + cl;
        float inv = g2[c] * rsqrtf(var2[c] + 1e-5f);
        float v = acc * inv + (be2[c] - mu2[c] * inv);
        ob[(size_t)cl * NPX] = fmaxf(v, 0.0f);
    }
}

// ---------------------------------------------------------------------------
extern "C" void kernel_launch(void* const* d_in, const int* in_sizes, int n_in,
                              void* d_out, int out_size, void* d_ws, size_t ws_size,
                              hipStream_t stream) {
    const float* x    = (const float*)d_in[0];
    const float* w1   = (const float*)d_in[1];
    const float* g1   = (const float*)d_in[2];
    const float* be1  = (const float*)d_in[3];
    const float* mu1  = (const float*)d_in[4];
    const float* var1 = (const float*)d_in[5];
    const float* w2   = (const float*)d_in[6];
    const float* b2   = (const float*)d_in[7];
    const float* g2   = (const float*)d_in[8];
    const float* be2  = (const float*)d_in[9];
    const float* mu2  = (const float*)d_in[10];
    const float* var2 = (const float*)d_in[11];
    float* outp = (float*)d_out;

    // ws layout: xpad (8*256*62*64*4 = 32.5 MB) then t (8*64*3136*4 = 6.4 MB)
    float* xpad = (float*)d_ws;
    float* t    = (float*)((char*)d_ws + (size_t)NB * NC * XPSLICE * sizeof(float));

    // K0: padded copy
    pad_kernel<<<NB * NC, 256, 0, stream>>>(x, xpad);
    // K1: conv1 + bn1 + relu
    conv1_kernel<<<dim3(NPX / 64, 2, NB), 256, 0, stream>>>(
        x, w1, g1, be1, mu1, var1, t);
    // K2: fused conv2 + involution + bn2 + relu
    involution_kernel<<<dim3(49, 4, NB), 256, 0, stream>>>(
        xpad, t, w2, b2, g2, be2, mu2, var2, outp);
}

// Round 5
// 153.389 us; speedup vs baseline: 3.4293x; 3.4293x over previous
//
#include <hip/hip_runtime.h>

// Problem constants
#define NB   8
#define NC   256
#define HW   56
#define NPX  3136          // 56*56
#define RED  64
#define NG   16
#define GC   16
#define KS   7
#define KK   49
#define PADK 3
#define XPH  62            // padded rows: 3 + 56 + 3
#define XPW  64            // padded row stride: 3 + 56 + 5 (aligned)
#define XPSLICE (XPH * XPW)   // 3968 floats per channel slice

// ---------------------------------------------------------------------------
// K0: zero-padded copy of x into xpad[b][c][62][64].
// ---------------------------------------------------------------------------
__global__ __launch_bounds__(256) void pad_kernel(
    const float* __restrict__ x, float* __restrict__ xpad) {
    int bc = blockIdx.x;                       // 0 .. NB*NC-1
    const float* xs = x + (size_t)bc * NPX;
    float* xd = xpad + (size_t)bc * XPSLICE;
#pragma unroll 4
    for (int e = threadIdx.x; e < XPSLICE; e += 256) {
        int row = e >> 6, col = e & 63;
        int h = row - PADK, w = col - PADK;
        float v = (h >= 0 && h < HW && w >= 0 && w < HW) ? xs[h * HW + w] : 0.0f;
        xd[e] = v;
    }
}

// ---------------------------------------------------------------------------
// K1: t = relu(bn1(conv1x1(x, w1)))   x:[B][256][3136] -> t:[B][64][3136]
// Block = 256 threads (4 waves) = 4 rq-slices of the SAME 64-px tile.
// wv is readfirstlane'd so w1 row reads compile to wave-uniform s_loads.
// ---------------------------------------------------------------------------
__global__ __launch_bounds__(256) void conv1_kernel(
    const float* __restrict__ x, const float* __restrict__ w1,
    const float* __restrict__ g1, const float* __restrict__ be1,
    const float* __restrict__ mu1, const float* __restrict__ var1,
    float* __restrict__ t) {
    int lane = threadIdx.x & 63;
    int wv   = __builtin_amdgcn_readfirstlane(threadIdx.x >> 6);  // 0..3 SGPR
    int px = blockIdx.x * 64 + lane;
    int rq = blockIdx.y * 4 + wv;              // 0..7 -> outputs rq*8..rq*8+7
    int b  = blockIdx.z;

    const float* xb = x + (size_t)b * NC * NPX + px;
    float acc[8];
#pragma unroll
    for (int j = 0; j < 8; ++j) acc[j] = 0.0f;

#pragma unroll 1
    for (int c0 = 0; c0 < NC; c0 += 16) {
        float xv[16];
#pragma unroll
        for (int i = 0; i < 16; ++i) xv[i] = xb[(size_t)(c0 + i) * NPX];
#pragma unroll
        for (int j = 0; j < 8; ++j) {
            const float* wrow = w1 + (rq * 8 + j) * NC + c0;   // s_load
#pragma unroll
            for (int i = 0; i < 16; ++i)
                acc[j] = fmaf(xv[i], wrow[i], acc[j]);
        }
    }

    float* tb = t + (size_t)b * RED * NPX + px;
#pragma unroll
    for (int j = 0; j < 8; ++j) {
        int o = rq * 8 + j;
        float inv = g1[o] * rsqrtf(var1[o] + 1e-5f);
        float v = acc[j] * inv + (be1[o] - mu1[o] * inv);
        tb[(size_t)o * NPX] = fmaxf(v, 0.0f);
    }
}

// ---------------------------------------------------------------------------
// K2: fused conv2(+bias) -> involution -> bn2 -> relu
// Grid (49 px-tiles, 8 group-pairs, 8 batches), block 512 = 8 waves.
// LDS: t-tile [64r][64px] (16 KB) + wgt [2g][49k][64px] (25 KB) = 41 KB
//      -> 3 blocks/CU, 24 waves/CU. No per-thread array > 13 floats.
// Phase A: wave (gl = wv>>2, q = wv&3) computes taps q*13..q*13+12 of group
//          gl: 13 reg accumulators, tv[8] batches from LDS, w2 s_loads,
//          ds_write results to wls.
// Phase B: wave (gl, q) handles channels q*4..q*4+3 of group gl: per tap
//          row read 7 wgt from LDS + 4x7 immediate-offset xpad loads (L1/L2),
//          oacc[4], bn2+relu, coalesced stores.
// ---------------------------------------------------------------------------
__global__ __launch_bounds__(512) void involution_kernel(
    const float* __restrict__ xpad, const float* __restrict__ t,
    const float* __restrict__ w2, const float* __restrict__ b2,
    const float* __restrict__ g2, const float* __restrict__ be2,
    const float* __restrict__ mu2, const float* __restrict__ var2,
    float* __restrict__ out) {
    __shared__ float tls[RED * 64];            // 16 KB  [r][px]
    __shared__ float wls[2 * KK * 64];         // 25 KB  [gl][k][px]

    int tid  = threadIdx.x;
    int lane = tid & 63;
    int wv   = __builtin_amdgcn_readfirstlane(tid >> 6);   // 0..7 in SGPR
    int px0  = blockIdx.x * 64;
    int gp   = blockIdx.y;                     // group pair 0..7
    int b    = blockIdx.z;
    int px = px0 + lane;
    int h = px / HW, w = px % HW;

    // ---- stage t tile into LDS (each wave stages 8 rows, coalesced) ----
    const float* tb = t + (size_t)b * RED * NPX + px0;
#pragma unroll
    for (int rr = 0; rr < 8; ++rr) {
        int row = wv * 8 + rr;
        tls[row * 64 + lane] = tb[(size_t)row * NPX + lane];
    }
    __syncthreads();

    int gl = wv >> 2;                          // local group 0/1 (SGPR)
    int q  = wv & 3;                           // quarter 0..3   (SGPR)
    int g  = gp * 2 + gl;
    int kbase = q * 13;                        // taps kbase..kbase+12 (<49)
    const float* wg = w2 + (size_t)g * KK * RED;   // wave-uniform base
    const float* bg = b2 + (size_t)g * KK;

    // ---- phase A: 13 wgt accumulators per lane ----
    float acc[13];
#pragma unroll
    for (int i = 0; i < 13; ++i) {
        int k = kbase + i;
        acc[i] = (k < KK) ? bg[k] : 0.0f;
    }
#pragma unroll 1
    for (int r0 = 0; r0 < RED; r0 += 8) {
        float tv[8];
#pragma unroll
        for (int j = 0; j < 8; ++j) tv[j] = tls[(r0 + j) * 64 + lane];
#pragma unroll
        for (int i = 0; i < 13; ++i) {
            int k = kbase + i;
            if (k < KK) {                      // uniform predicate
                const float* wk = wg + k * RED + r0;   // s_load row
#pragma unroll
                for (int j = 0; j < 8; ++j)
                    acc[i] = fmaf(tv[j], wk[j], acc[i]);
            }
        }
    }
    {
        float* wl = wls + gl * (KK * 64);
#pragma unroll
        for (int i = 0; i < 13; ++i) {
            int k = kbase + i;
            if (k < KK) wl[k * 64 + lane] = acc[i];
        }
    }
    __syncthreads();

    // ---- phase B: involution for 4 channels ----
    int cl0 = q * 4;
    const float* wlg = wls + gl * (KK * 64);
    const float* xgb = xpad + ((size_t)b * NC + (size_t)(g * GC + cl0)) * XPSLICE
                     + h * XPW + w;
    float* ob = out + ((size_t)b * NC + (size_t)(g * GC + cl0)) * NPX + px;

    float oacc[4] = {0.0f, 0.0f, 0.0f, 0.0f};
#pragma unroll 1
    for (int i = 0; i < KS; ++i) {
        float wk7[KS];
#pragma unroll
        for (int j = 0; j < KS; ++j) wk7[j] = wlg[(i * KS + j) * 64 + lane];
#pragma unroll
        for (int cl = 0; cl < 4; ++cl) {
            const float* xr = xgb + (size_t)cl * XPSLICE + i * XPW;
            float s0 = fmaf(wk7[0], xr[0], oacc[cl]);
            float s1 = wk7[1] * xr[1];
            s0 = fmaf(wk7[2], xr[2], s0);
            s1 = fmaf(wk7[3], xr[3], s1);
            s0 = fmaf(wk7[4], xr[4], s0);
            s1 = fmaf(wk7[5], xr[5], s1);
            s0 = fmaf(wk7[6], xr[6], s0);
            oacc[cl] = s0 + s1;
        }
    }
#pragma unroll
    for (int cl = 0; cl < 4; ++cl) {
        int c = g * GC + cl0 + cl;
        float inv = g2[c] * rsqrtf(var2[c] + 1e-5f);
        float v = oacc[cl] * inv + (be2[c] - mu2[c] * inv);
        ob[(size_t)cl * NPX] = fmaxf(v, 0.0f);
    }
}

// ---------------------------------------------------------------------------
extern "C" void kernel_launch(void* const* d_in, const int* in_sizes, int n_in,
                              void* d_out, int out_size, void* d_ws, size_t ws_size,
                              hipStream_t stream) {
    const float* x    = (const float*)d_in[0];
    const float* w1   = (const float*)d_in[1];
    const float* g1   = (const float*)d_in[2];
    const float* be1  = (const float*)d_in[3];
    const float* mu1  = (const float*)d_in[4];
    const float* var1 = (const float*)d_in[5];
    const float* w2   = (const float*)d_in[6];
    const float* b2   = (const float*)d_in[7];
    const float* g2   = (const float*)d_in[8];
    const float* be2  = (const float*)d_in[9];
    const float* mu2  = (const float*)d_in[10];
    const float* var2 = (const float*)d_in[11];
    float* outp = (float*)d_out;

    // ws layout: xpad (8*256*62*64*4 = 32.5 MB) then t (8*64*3136*4 = 6.4 MB)
    float* xpad = (float*)d_ws;
    float* t    = (float*)((char*)d_ws + (size_t)NB * NC * XPSLICE * sizeof(float));

    // K0: padded copy
    pad_kernel<<<NB * NC, 256, 0, stream>>>(x, xpad);
    // K1: conv1 + bn1 + relu
    conv1_kernel<<<dim3(NPX / 64, 2, NB), 256, 0, stream>>>(
        x, w1, g1, be1, mu1, var1, t);
    // K2: fused conv2 + involution + bn2 + relu
    involution_kernel<<<dim3(49, 8, NB), 512, 0, stream>>>(
        xpad, t, w2, b2, g2, be2, mu2, var2, outp);
}

// Round 6
// 120.138 us; speedup vs baseline: 4.3784x; 1.2768x over previous
//
#include <hip/hip_runtime.h>
#include <hip/hip_bf16.h>

// Problem constants
#define NB   8
#define NC   256
#define HW   56
#define NPX  3136          // 56*56
#define RED  64
#define NG   16
#define GC   16
#define KS   7
#define KK   49
#define PADK 3
#define XPH  62            // padded rows: 3 + 56 + 3
#define XPW  64            // padded row stride
#define XPSLICE (XPH * XPW)   // 3968 floats per channel slice
#define TLS_STRIDE 72      // bf16 r-stride for transposed t tile (pad vs 64)
#define WLS_STRIDE 65      // f32 px-stride for wgt tile (pad vs 64)

typedef float f32x4 __attribute__((ext_vector_type(4)));
typedef short short8 __attribute__((ext_vector_type(8)));

// ---------------------------------------------------------------------------
// K0a: zero-padded copy of x into xpad[b][c][62][64] (fp32).
// ---------------------------------------------------------------------------
__global__ __launch_bounds__(256) void pad_kernel(
    const float* __restrict__ x, float* __restrict__ xpad) {
    int bc = blockIdx.x;                       // 0 .. NB*NC-1
    const float* xs = x + (size_t)bc * NPX;
    float* xd = xpad + (size_t)bc * XPSLICE;
#pragma unroll 4
    for (int e = threadIdx.x; e < XPSLICE; e += 256) {
        int row = e >> 6, col = e & 63;
        int h = row - PADK, w = col - PADK;
        float v = (h >= 0 && h < HW && w >= 0 && w < HW) ? xs[h * HW + w] : 0.0f;
        xd[e] = v;
    }
}

// ---------------------------------------------------------------------------
// K0b: w2 [16g*49][64] fp32 -> w2bf [g][64m][64k] bf16 (rows 49..63 zero).
// ---------------------------------------------------------------------------
__global__ __launch_bounds__(256) void prep_w2_kernel(
    const float* __restrict__ w2, __hip_bfloat16* __restrict__ w2bf) {
    int g = blockIdx.x;                        // 0..15
#pragma unroll 4
    for (int e = threadIdx.x; e < 64 * 64; e += 256) {
        int m = e >> 6, k = e & 63;
        float v = (m < KK) ? w2[((size_t)g * KK + m) * RED + k] : 0.0f;
        w2bf[(size_t)g * 4096 + e] = __float2bfloat16(v);
    }
}

// ---------------------------------------------------------------------------
// K1: t = relu(bn1(conv1x1(x, w1))) -> bf16   x:[B][256][3136] -> t:[B][64][3136]
// ---------------------------------------------------------------------------
__global__ __launch_bounds__(256) void conv1_kernel(
    const float* __restrict__ x, const float* __restrict__ w1,
    const float* __restrict__ g1, const float* __restrict__ be1,
    const float* __restrict__ mu1, const float* __restrict__ var1,
    __hip_bfloat16* __restrict__ t) {
    int lane = threadIdx.x & 63;
    int wv   = __builtin_amdgcn_readfirstlane(threadIdx.x >> 6);  // 0..3 SGPR
    int px = blockIdx.x * 64 + lane;
    int rq = blockIdx.y * 4 + wv;              // 0..7 -> outputs rq*8..rq*8+7
    int b  = blockIdx.z;

    const float* xb = x + (size_t)b * NC * NPX + px;
    float acc[8];
#pragma unroll
    for (int j = 0; j < 8; ++j) acc[j] = 0.0f;

#pragma unroll 1
    for (int c0 = 0; c0 < NC; c0 += 16) {
        float xv[16];
#pragma unroll
        for (int i = 0; i < 16; ++i) xv[i] = xb[(size_t)(c0 + i) * NPX];
#pragma unroll
        for (int j = 0; j < 8; ++j) {
            const float* wrow = w1 + (rq * 8 + j) * NC + c0;   // s_load
#pragma unroll
            for (int i = 0; i < 16; ++i)
                acc[j] = fmaf(xv[i], wrow[i], acc[j]);
        }
    }

    __hip_bfloat16* tb = t + (size_t)b * RED * NPX + px;
#pragma unroll
    for (int j = 0; j < 8; ++j) {
        int o = rq * 8 + j;
        float inv = g1[o] * rsqrtf(var1[o] + 1e-5f);
        float v = acc[j] * inv + (be1[o] - mu1[o] * inv);
        tb[(size_t)o * NPX] = __float2bfloat16(fmaxf(v, 0.0f));
    }
}

// ---------------------------------------------------------------------------
// K2: fused conv2(MFMA) -> involution -> bn2 -> relu
// Grid (49 px-tiles, 8 group-pairs, 8 batches), block 512 = 8 waves.
// LDS: tls bf16 [64px][72r] (9.2 KB, transposed for B-frags)
//      wls f32  [2g][49k][65px] (25.5 KB)   total 34.7 KB.
// Phase A (MFMA): wave (gl = wv>>2, ni = wv&3): C tile = wgt[4x16 m][16 px]
//   via 4 m-tiles x 2 k-steps of mfma_f32_16x16x32_bf16.
//   A = w2bf[g] (16B-contig frags, L1), B = tls (ds_read_b128 frags).
//   C layout: px = lane&15 (+ni*16), k = mt*16 + (lane>>4)*4 + reg.
// Phase B: wave (gl, q): channels q*4..+3 of group gl; per tap row read 7
//   wgt from LDS (+ s_load bias), 28 imm-offset xpad loads, oacc[4], bn2+relu.
// ---------------------------------------------------------------------------
__global__ __launch_bounds__(512) void involution_kernel(
    const float* __restrict__ xpad, const __hip_bfloat16* __restrict__ t,
    const __hip_bfloat16* __restrict__ w2bf, const float* __restrict__ b2,
    const float* __restrict__ g2, const float* __restrict__ be2,
    const float* __restrict__ mu2, const float* __restrict__ var2,
    float* __restrict__ out) {
    __shared__ short tls[64 * TLS_STRIDE];         // bf16 [px][r]
    __shared__ float wls[2 * KK * WLS_STRIDE];     // f32  [gl][k][px]

    int tid  = threadIdx.x;
    int lane = tid & 63;
    int wv   = __builtin_amdgcn_readfirstlane(tid >> 6);   // 0..7 SGPR
    int px0  = blockIdx.x * 64;
    int gp   = blockIdx.y;                     // group pair 0..7
    int b    = blockIdx.z;
    int px = px0 + lane;
    int h = px / HW, w = px % HW;

    // ---- stage t tile TRANSPOSED into LDS: tls[px][r] (bf16 pairs) ----
    const unsigned short* tb =
        (const unsigned short*)t + (size_t)b * RED * NPX + px0;
#pragma unroll
    for (int rr = 0; rr < 4; ++rr) {
        int r = wv * 8 + rr * 2;               // even
        unsigned int lo = tb[(size_t)r * NPX + lane];
        unsigned int hi = tb[(size_t)(r + 1) * NPX + lane];
        *(unsigned int*)&tls[lane * TLS_STRIDE + r] = lo | (hi << 16);
    }
    __syncthreads();

    int gl = wv >> 2;                          // local group 0/1 (SGPR)
    int g  = gp * 2 + gl;

    // ---- phase A: MFMA wgt = w2g[49x64] . t[64x64px] ----
    {
        int ni = wv & 3;                       // N-tile 0..3 (SGPR)
        int l15 = lane & 15, l4 = lane >> 4;
        // B-frags from transposed tls: col px = ni*16+l15, k = l4*8 + i
        const short* tp = tls + (ni * 16 + l15) * TLS_STRIDE + l4 * 8;
        short8 bfr0 = *(const short8*)(tp);
        short8 bfr1 = *(const short8*)(tp + 32);

        const short* wA = (const short*)w2bf + (size_t)g * 4096;
        f32x4 acc0 = {0,0,0,0}, acc1 = {0,0,0,0}, acc2 = {0,0,0,0}, acc3 = {0,0,0,0};
#pragma unroll
        for (int mt = 0; mt < 4; ++mt) {
            const short* ap = wA + (mt * 16 + l15) * 64 + l4 * 8;
            short8 a0 = *(const short8*)(ap);
            short8 a1 = *(const short8*)(ap + 32);
            f32x4 a = (mt == 0) ? acc0 : (mt == 1) ? acc1 : (mt == 2) ? acc2 : acc3;
            a = __builtin_amdgcn_mfma_f32_16x16x32_bf16(a0, bfr0, a, 0, 0, 0);
            a = __builtin_amdgcn_mfma_f32_16x16x32_bf16(a1, bfr1, a, 0, 0, 0);
            if (mt == 0) acc0 = a; else if (mt == 1) acc1 = a;
            else if (mt == 2) acc2 = a; else acc3 = a;
        }
        // write C -> wls[gl][k][px], k = mt*16 + l4*4 + reg (k<49)
        float* wl = wls + gl * (KK * WLS_STRIDE) + ni * 16 + l15;
#pragma unroll
        for (int mt = 0; mt < 4; ++mt) {
            f32x4 a = (mt == 0) ? acc0 : (mt == 1) ? acc1 : (mt == 2) ? acc2 : acc3;
#pragma unroll
            for (int r = 0; r < 4; ++r) {
                int k = mt * 16 + l4 * 4 + r;
                if (k < KK) wl[k * WLS_STRIDE] = a[r];
            }
        }
    }
    __syncthreads();

    // ---- phase B: involution + bias + bn2 + relu ----
    int q = wv & 3;
    int cl0 = q * 4;
    const float* wlg = wls + gl * (KK * WLS_STRIDE);
    const float* bg  = b2 + (size_t)g * KK;    // wave-uniform -> s_load
    const float* xgb = xpad + ((size_t)b * NC + (size_t)(g * GC + cl0)) * XPSLICE
                     + h * XPW + w;
    float* ob = out + ((size_t)b * NC + (size_t)(g * GC + cl0)) * NPX + px;

    float oacc[4] = {0.0f, 0.0f, 0.0f, 0.0f};
#pragma unroll 1
    for (int i = 0; i < KS; ++i) {
        float wk7[KS];
#pragma unroll
        for (int j = 0; j < KS; ++j)
            wk7[j] = wlg[(i * KS + j) * WLS_STRIDE + lane] + bg[i * KS + j];
#pragma unroll
        for (int cl = 0; cl < 4; ++cl) {
            const float* xr = xgb + (size_t)cl * XPSLICE + i * XPW;
            float s0 = fmaf(wk7[0], xr[0], oacc[cl]);
            float s1 = wk7[1] * xr[1];
            s0 = fmaf(wk7[2], xr[2], s0);
            s1 = fmaf(wk7[3], xr[3], s1);
            s0 = fmaf(wk7[4], xr[4], s0);
            s1 = fmaf(wk7[5], xr[5], s1);
            s0 = fmaf(wk7[6], xr[6], s0);
            oacc[cl] = s0 + s1;
        }
    }
#pragma unroll
    for (int cl = 0; cl < 4; ++cl) {
        int c = g * GC + cl0 + cl;
        float inv = g2[c] * rsqrtf(var2[c] + 1e-5f);
        float v = oacc[cl] * inv + (be2[c] - mu2[c] * inv);
        ob[(size_t)cl * NPX] = fmaxf(v, 0.0f);
    }
}

// ---------------------------------------------------------------------------
extern "C" void kernel_launch(void* const* d_in, const int* in_sizes, int n_in,
                              void* d_out, int out_size, void* d_ws, size_t ws_size,
                              hipStream_t stream) {
    const float* x    = (const float*)d_in[0];
    const float* w1   = (const float*)d_in[1];
    const float* g1   = (const float*)d_in[2];
    const float* be1  = (const float*)d_in[3];
    const float* mu1  = (const float*)d_in[4];
    const float* var1 = (const float*)d_in[5];
    const float* w2   = (const float*)d_in[6];
    const float* b2   = (const float*)d_in[7];
    const float* g2   = (const float*)d_in[8];
    const float* be2  = (const float*)d_in[9];
    const float* mu2  = (const float*)d_in[10];
    const float* var2 = (const float*)d_in[11];
    float* outp = (float*)d_out;

    // ws: xpad f32 (32.5 MB) | t bf16 (3.2 MB) | w2bf bf16 (128 KB)
    float* xpad = (float*)d_ws;
    char* p = (char*)d_ws + (size_t)NB * NC * XPSLICE * sizeof(float);
    __hip_bfloat16* t = (__hip_bfloat16*)p;
    p += (size_t)NB * RED * NPX * sizeof(__hip_bfloat16);
    __hip_bfloat16* w2bf = (__hip_bfloat16*)p;

    prep_w2_kernel<<<NG, 256, 0, stream>>>(w2, w2bf);
    pad_kernel<<<NB * NC, 256, 0, stream>>>(x, xpad);
    conv1_kernel<<<dim3(NPX / 64, 2, NB), 256, 0, stream>>>(
        x, w1, g1, be1, mu1, var1, t);
    involution_kernel<<<dim3(49, 8, NB), 512, 0, stream>>>(
        xpad, t, w2bf, b2, g2, be2, mu2, var2, outp);
}

// Round 7
// 119.799 us; speedup vs baseline: 4.3908x; 1.0028x over previous
//
#include <hip/hip_runtime.h>
#include <hip/hip_bf16.h>

// Problem constants
#define NB   8
#define NC   256
#define HW   56
#define NPX  3136          // 56*56
#define RED  64
#define NG   16
#define GC   16
#define KS   7
#define KK   49
#define PADK 3
#define XPH  62            // padded rows: 3 + 56 + 3
#define XPW  64            // padded row stride
#define XPSLICE (XPH * XPW)   // 3968 floats per channel slice
#define TLS_STRIDE 72      // bf16 r-stride for transposed t tile
#define WLS_STRIDE 65      // f32 px-stride for wgt tile

typedef float f32x4 __attribute__((ext_vector_type(4)));
typedef short short8 __attribute__((ext_vector_type(8)));
typedef unsigned int u32x4 __attribute__((ext_vector_type(4)));

// ---------------------------------------------------------------------------
// K0a: zero only the BORDER of xpad (832 elems/slice); interior is written
// by conv1_kernel. Border: rows 0-2, 59-61 full; rows 3-58 cols {0,1,2,59..63}.
// ---------------------------------------------------------------------------
__global__ __launch_bounds__(256) void border_kernel(float* __restrict__ xpad) {
    int bc = blockIdx.x;                       // 0 .. NB*NC-1
    float* xd = xpad + (size_t)bc * XPSLICE;
#pragma unroll
    for (int e = threadIdx.x; e < 832; e += 256) {
        int row, col;
        if (e < 192)      { row = e >> 6;              col = e & 63; }
        else if (e < 384) { int f = e - 192; row = 59 + (f >> 6); col = f & 63; }
        else              { int f = e - 384; row = 3 + (f >> 3);
                            int c8 = f & 7;  col = (c8 < 3) ? c8 : 56 + c8; }
        xd[row * XPW + col] = 0.0f;
    }
}

// ---------------------------------------------------------------------------
// K0b: w2 [16g*49][64] fp32 -> w2bf [g][64m][64k] bf16 (rows 49..63 zero).
// ---------------------------------------------------------------------------
__global__ __launch_bounds__(256) void prep_w2_kernel(
    const float* __restrict__ w2, __hip_bfloat16* __restrict__ w2bf) {
    int g = blockIdx.x;                        // 0..15
#pragma unroll 4
    for (int e = threadIdx.x; e < 64 * 64; e += 256) {
        int m = e >> 6, k = e & 63;
        float v = (m < KK) ? w2[((size_t)g * KK + m) * RED + k] : 0.0f;
        w2bf[(size_t)g * 4096 + e] = __float2bfloat16(v);
    }
}

// ---------------------------------------------------------------------------
// K1: t = relu(bn1(conv1x1(x, w1))) -> bf16, AND scatter x into xpad interior.
// Grid 392 blocks (XCD-swizzled: each XCD owns one batch) x 512 thr (8 waves).
// Wave wv computes outputs wv*8..wv*8+7 for a 64-px tile; x tile read once
// per block (waves share via L1). Wave 0 also writes xpad interior.
// ---------------------------------------------------------------------------
__global__ __launch_bounds__(512) void conv1_kernel(
    const float* __restrict__ x, const float* __restrict__ w1,
    const float* __restrict__ g1, const float* __restrict__ be1,
    const float* __restrict__ mu1, const float* __restrict__ var1,
    __hip_bfloat16* __restrict__ t, float* __restrict__ xpad) {
    int lane = threadIdx.x & 63;
    int wv   = __builtin_amdgcn_readfirstlane(threadIdx.x >> 6);  // 0..7 SGPR
    // XCD swizzle: 392 = 8 * 49; logical = b*49 + tile
    int wgid = blockIdx.x;
    int swz  = (wgid & 7) * 49 + (wgid >> 3);
    int tile = swz % 49;
    int b    = swz / 49;
    int px = tile * 64 + lane;
    int h = px / HW, w = px % HW;

    const float* xb = x + (size_t)b * NC * NPX + px;
    float* xpw = xpad + (size_t)b * NC * XPSLICE + (h + PADK) * XPW + (w + PADK);

    float acc[8];
#pragma unroll
    for (int j = 0; j < 8; ++j) acc[j] = 0.0f;

#pragma unroll 1
    for (int c0 = 0; c0 < NC; c0 += 16) {
        float xv[16];
#pragma unroll
        for (int i = 0; i < 16; ++i) xv[i] = xb[(size_t)(c0 + i) * NPX];
        if (wv == 0) {                         // wave-uniform branch
#pragma unroll
            for (int i = 0; i < 16; ++i)
                xpw[(size_t)(c0 + i) * XPSLICE] = xv[i];
        }
#pragma unroll
        for (int j = 0; j < 8; ++j) {
            const float* wrow = w1 + (wv * 8 + j) * NC + c0;   // s_load
#pragma unroll
            for (int i = 0; i < 16; ++i)
                acc[j] = fmaf(xv[i], wrow[i], acc[j]);
        }
    }

    __hip_bfloat16* tb = t + (size_t)b * RED * NPX + px;
#pragma unroll
    for (int j = 0; j < 8; ++j) {
        int o = wv * 8 + j;
        float inv = g1[o] * rsqrtf(var1[o] + 1e-5f);
        float v = acc[j] * inv + (be1[o] - mu1[o] * inv);
        tb[(size_t)o * NPX] = __float2bfloat16(fmaxf(v, 0.0f));
    }
}

// ---------------------------------------------------------------------------
// K2: fused conv2(MFMA) -> involution -> bn2 -> relu
// Grid 3136 1D (XCD-swizzled: each XCD owns one batch -> xpad[b] L2-resident),
// block 512 = 8 waves. LDS: tls bf16 [64px][72r] + wls f32 [2g][49k][65px].
// Phase A (MFMA): wave (gl,ni) computes wgt[4x16 m][16 px]; bias folded into
//   the C-write. t staged via ONE ds_write_b128/wave-row (conflict-free).
// Phase B: wave (gl,q): 4 channels; per tap row TWO f32x4 loads (8 floats
//   cover taps 0..6), 2 FMA chains, bn2+relu, coalesced stores.
// ---------------------------------------------------------------------------
__global__ __launch_bounds__(512) void involution_kernel(
    const float* __restrict__ xpad, const __hip_bfloat16* __restrict__ t,
    const __hip_bfloat16* __restrict__ w2bf, const float* __restrict__ b2,
    const float* __restrict__ g2, const float* __restrict__ be2,
    const float* __restrict__ mu2, const float* __restrict__ var2,
    float* __restrict__ out) {
    __shared__ __align__(16) short tls[64 * TLS_STRIDE];   // bf16 [px][r]
    __shared__ float wls[2 * KK * WLS_STRIDE];             // f32  [gl][k][px]

    int tid  = threadIdx.x;
    int lane = tid & 63;
    int wv   = __builtin_amdgcn_readfirstlane(tid >> 6);   // 0..7 SGPR
    // XCD swizzle: 3136 = 8 * 392; logical = b*392 + gp*49 + tile
    int wgid = blockIdx.x;
    int swz  = (wgid & 7) * 392 + (wgid >> 3);
    int tile = swz % 49;
    int gp   = (swz / 49) & 7;
    int b    = swz / 392;
    int px0 = tile * 64;
    int px = px0 + lane;
    int h = px / HW, w = px % HW;

    // ---- stage t tile transposed: one conflict-free ds_write_b128 per lane ----
    const unsigned short* tb =
        (const unsigned short*)t + (size_t)b * RED * NPX + px0;
    {
        unsigned int pk[4];
#pragma unroll
        for (int j = 0; j < 4; ++j) {
            unsigned int lo = tb[(size_t)(wv * 8 + 2 * j)     * NPX + lane];
            unsigned int hi = tb[(size_t)(wv * 8 + 2 * j + 1) * NPX + lane];
            pk[j] = lo | (hi << 16);
        }
        u32x4 v = {pk[0], pk[1], pk[2], pk[3]};
        *(u32x4*)&tls[lane * TLS_STRIDE + wv * 8] = v;   // byte = lane*144+wv*16
    }
    __syncthreads();

    int gl = wv >> 2;                          // local group 0/1 (SGPR)
    int g  = gp * 2 + gl;
    const float* bg = b2 + (size_t)g * KK;     // wave-uniform -> s_load

    // ---- phase A: MFMA wgt = w2g[49x64] . t[64x64px] (+bias) ----
    {
        int ni = wv & 3;                       // N-tile 0..3 (SGPR)
        int l15 = lane & 15, l4 = lane >> 4;
        const short* tp = tls + (ni * 16 + l15) * TLS_STRIDE + l4 * 8;
        short8 bfr0 = *(const short8*)(tp);
        short8 bfr1 = *(const short8*)(tp + 32);

        const short* wA = (const short*)w2bf + (size_t)g * 4096;
        f32x4 acc0 = {0,0,0,0}, acc1 = {0,0,0,0}, acc2 = {0,0,0,0}, acc3 = {0,0,0,0};
#pragma unroll
        for (int mt = 0; mt < 4; ++mt) {
            const short* ap = wA + (mt * 16 + l15) * 64 + l4 * 8;
            short8 a0 = *(const short8*)(ap);
            short8 a1 = *(const short8*)(ap + 32);
            f32x4 a = (mt == 0) ? acc0 : (mt == 1) ? acc1 : (mt == 2) ? acc2 : acc3;
            a = __builtin_amdgcn_mfma_f32_16x16x32_bf16(a0, bfr0, a, 0, 0, 0);
            a = __builtin_amdgcn_mfma_f32_16x16x32_bf16(a1, bfr1, a, 0, 0, 0);
            if (mt == 0) acc0 = a; else if (mt == 1) acc1 = a;
            else if (mt == 2) acc2 = a; else acc3 = a;
        }
        float* wl = wls + gl * (KK * WLS_STRIDE) + ni * 16 + l15;
#pragma unroll
        for (int mt = 0; mt < 4; ++mt) {
            f32x4 a = (mt == 0) ? acc0 : (mt == 1) ? acc1 : (mt == 2) ? acc2 : acc3;
#pragma unroll
            for (int r = 0; r < 4; ++r) {
                int k = mt * 16 + l4 * 4 + r;
                if (k < KK) wl[k * WLS_STRIDE] = a[r] + bg[k];  // bias folded
            }
        }
    }
    __syncthreads();

    // ---- phase B: involution + bn2 + relu ----
    int q = wv & 3;
    int cl0 = q * 4;
    const float* wlg = wls + gl * (KK * WLS_STRIDE);
    const float* xgb = xpad + ((size_t)b * NC + (size_t)(g * GC + cl0)) * XPSLICE
                     + h * XPW + w;
    float* ob = out + ((size_t)b * NC + (size_t)(g * GC + cl0)) * NPX + px;

    float oacc[4] = {0.0f, 0.0f, 0.0f, 0.0f};
#pragma unroll 1
    for (int i = 0; i < KS; ++i) {
        float wk7[KS];
#pragma unroll
        for (int j = 0; j < KS; ++j)
            wk7[j] = wlg[(i * KS + j) * WLS_STRIDE + lane];
#pragma unroll
        for (int cl = 0; cl < 4; ++cl) {
            const float* xr = xgb + (size_t)cl * XPSLICE + i * XPW;
            f32x4 v0 = *(const f32x4*)(xr);        // taps 0..3 (dword-aligned ok)
            f32x4 v1 = *(const f32x4*)(xr + 4);    // taps 4..6 (+1 spare, in-row)
            float s0 = fmaf(wk7[0], v0.x, oacc[cl]);
            float s1 = wk7[1] * v0.y;
            s0 = fmaf(wk7[2], v0.z, s0);
            s1 = fmaf(wk7[3], v0.w, s1);
            s0 = fmaf(wk7[4], v1.x, s0);
            s1 = fmaf(wk7[5], v1.y, s1);
            s0 = fmaf(wk7[6], v1.z, s0);
            oacc[cl] = s0 + s1;
        }
    }
#pragma unroll
    for (int cl = 0; cl < 4; ++cl) {
        int c = g * GC + cl0 + cl;
        float inv = g2[c] * rsqrtf(var2[c] + 1e-5f);
        float v = oacc[cl] * inv + (be2[c] - mu2[c] * inv);
        ob[(size_t)cl * NPX] = fmaxf(v, 0.0f);
    }
}

// ---------------------------------------------------------------------------
extern "C" void kernel_launch(void* const* d_in, const int* in_sizes, int n_in,
                              void* d_out, int out_size, void* d_ws, size_t ws_size,
                              hipStream_t stream) {
    const float* x    = (const float*)d_in[0];
    const float* w1   = (const float*)d_in[1];
    const float* g1   = (const float*)d_in[2];
    const float* be1  = (const float*)d_in[3];
    const float* mu1  = (const float*)d_in[4];
    const float* var1 = (const float*)d_in[5];
    const float* w2   = (const float*)d_in[6];
    const float* b2   = (const float*)d_in[7];
    const float* g2   = (const float*)d_in[8];
    const float* be2  = (const float*)d_in[9];
    const float* mu2  = (const float*)d_in[10];
    const float* var2 = (const float*)d_in[11];
    float* outp = (float*)d_out;

    // ws: xpad f32 (32.5 MB) | t bf16 (3.2 MB) | w2bf bf16 (128 KB)
    float* xpad = (float*)d_ws;
    char* p = (char*)d_ws + (size_t)NB * NC * XPSLICE * sizeof(float);
    __hip_bfloat16* t = (__hip_bfloat16*)p;
    p += (size_t)NB * RED * NPX * sizeof(__hip_bfloat16);
    __hip_bfloat16* w2bf = (__hip_bfloat16*)p;

    prep_w2_kernel<<<NG, 256, 0, stream>>>(w2, w2bf);
    border_kernel<<<NB * NC, 256, 0, stream>>>(xpad);
    conv1_kernel<<<392, 512, 0, stream>>>(
        x, w1, g1, be1, mu1, var1, t, xpad);
    involution_kernel<<<3136, 512, 0, stream>>>(
        xpad, t, w2bf, b2, g2, be2, mu2, var2, outp);
}